// Round 5
// baseline (232.528 us; speedup 1.0000x reference)
//
#include <hip/hip_runtime.h>
#include <stdint.h>

// Problem constants: B=16, K=8, C=64, L=2048
#define BB 16
#define KK 8
#define CC 64
#define LL 2048

constexpr int CL  = CC * LL;             // 131072 elems per batch
constexpr int QPB = CL / 4;              // 32768 quads per batch
constexpr int QBLK = 1024;               // quads per block (4 waves x 64 lanes x 4 quads)
constexpr int NBLOCKS = (BB * QPB) / QBLK;  // 512

#define SIG_OFF 0.11920292202211755f     // 1 - sigmoid(2) = sigmoid(-2)
#define LOG_EPS -16.11809565095832f      // logf(1e-7)

typedef float f32x4 __attribute__((ext_vector_type(4)));

__device__ __forceinline__ float frcp(float x) { return __builtin_amdgcn_rcpf(x); }

__global__ void init_sldj_kernel(const float* __restrict__ sldj_in,
                                 float* __restrict__ sldj_out) {
    int i = threadIdx.x;
    if (i < BB) sldj_out[i] = sldj_in[i];
}

// R5: address-stream restructure (DRAM page locality), not register depth.
//  - k-SEQUENTIAL: only pi/mu/s of ONE k (3 regions/batch) active at a time,
//    vs all 24 at once in R0-R4.
//  - Q=4 quads/thread: each wave reads 4KB CONTIGUOUS per stream visit
//    (4 back-to-back dwordx4, offsets 0/1024/2048/3072 fold into the instr),
//    vs 1KB in R0-R4 -> 2-4 full DRAM pages per burst.
//  - per-block k-rotation: blocks start at k=(blockIdx&7), spreading the
//    chip's instantaneous reads over all k-regions uniformly (no hotspot).
// Sums over k are commutative; rotation only reorders fp adds (tolerance ok).
__global__ __launch_bounds__(256, 2) void coupling_kernel(
    const float* __restrict__ x,
    const float* __restrict__ a,
    const float* __restrict__ bv,
    const float* __restrict__ pi,
    const float* __restrict__ mu,
    const float* __restrict__ s,
    float* __restrict__ out,
    float* __restrict__ sldj_out) {

    const int tid  = threadIdx.x;
    const int lane = tid & 63;
    const int wid  = tid >> 6;
    // Thread's 4 quads: q0 + 64*i  (wave covers 256 consecutive quads = 4KB/stream)
    const int q0   = blockIdx.x * QBLK + wid * 256 + lane;
    const int b    = q0 >> 15;               // batch (QBLK divides QPB)
    const int e0   = q0 * 4;                 // flat elem index of first quad
    const int rem0 = e0 - b * CL;

    // x for the 4 quads stays live across the whole k-loop (16 VGPRs).
    f32x4 x4[4];
#pragma unroll
    for (int i = 0; i < 4; ++i) x4[i] = *(const f32x4*)(x + e0 + i * 256);

    // Accumulators [quad i][elem e]:
    //   Spi = sum_k e^{pi_k}
    //   Nc  = sum_k e^{pi_k} * sigmoid(z_k)            -> u   = Nc/Spi
    //   N1  = sum_k e^{pi_k} * (1 - sigmoid(z_k))      -> 1-u = N1/Spi
    //   N1 kept separate (NOT Spi-Nc): avoids cancellation when u -> 1.
    //   Np  = sum_k e^{pi_k} * e^{-s_k} * sig*(1-sig)  -> pdf = Np/Spi
    float Spi[4][4], Nc[4][4], N1[4][4], Np[4][4];
#pragma unroll
    for (int i = 0; i < 4; ++i)
#pragma unroll
        for (int e = 0; e < 4; ++e) {
            Spi[i][e] = 0.f; Nc[i][e] = 0.f; N1[i][e] = 0.f; Np[i][e] = 0.f;
        }

    const int kstart = blockIdx.x & 7;       // de-phase regions across blocks

#pragma unroll
    for (int kk = 0; kk < KK; ++kk) {
        const int k = (kstart + kk) & (KK - 1);
        const int kb = (b * KK + k) * CL + rem0;

        // 12 loads: 3 streams x 4KB contiguous per wave, back-to-back.
        f32x4 p4[4], m4[4], s4[4];
#pragma unroll
        for (int i = 0; i < 4; ++i) p4[i] = *(const f32x4*)(pi + kb + i * 256);
#pragma unroll
        for (int i = 0; i < 4; ++i) m4[i] = *(const f32x4*)(mu + kb + i * 256);
#pragma unroll
        for (int i = 0; i < 4; ++i) s4[i] = *(const f32x4*)(s  + kb + i * 256);

#pragma unroll
        for (int i = 0; i < 4; ++i) {
#pragma unroll
            for (int e = 0; e < 4; ++e) {
                const float p      = p4[i][e];
                const float m      = m4[i][e];
                const float sk     = s4[i][e];
                const float invstd = __expf(-sk);
                const float z      = (x4[i][e] - m) * invstd;

                // stable sigmoid via t = e^{-|z|}
                const float t  = __expf(-fabsf(z));
                const float r  = frcp(1.f + t);
                const float tr = t * r;
                const float sig  = (z >= 0.f) ? r  : tr;
                const float osig = (z >= 0.f) ? tr : r;

                const float ek = __expf(p);
                Spi[i][e] += ek;
                Nc[i][e]  += ek * sig;
                N1[i][e]  += ek * osig;
                Np[i][e]  += ek * invstd * sig * osig;
            }
        }
    }

    // Epilogue: a/b loaded now (their regs overlap the freed p/m/s).
    float contrib = 0.f;
#pragma unroll
    for (int i = 0; i < 4; ++i) {
        const f32x4 a4 = *(const f32x4*)(a  + e0 + i * 256);
        const f32x4 b4 = *(const f32x4*)(bv + e0 + i * 256);
        f32x4 out4;
#pragma unroll
        for (int e = 0; e < 4; ++e) {
            const float lSpi = __logf(Spi[i][e]);
            const float lu   = fmaxf(__logf(Nc[i][e]) - lSpi, LOG_EPS);
            const float lomu = fmaxf(__logf(N1[i][e]) - lSpi, LOG_EPS);
            const float y        = lu - lomu;     // logit
            const float ldj_term = -lu - lomu;
            const float log_pdf  = __logf(Np[i][e]) - lSpi;

            // scale = sigmoid(a+2) + sigmoid(-2)
            const float ae = a4[e] + 2.f;
            const float t2 = __expf(-fabsf(ae));
            const float r2 = frcp(1.f + t2);
            const float sc = ((ae >= 0.f) ? r2 : t2 * r2) + SIG_OFF;

            out4[e] = (y + b4[e]) * sc;
            contrib += log_pdf + ldj_term + __logf(sc);
        }
        *(f32x4*)(out + e0 + i * 256) = out4;
    }

    // ---- block reduction, one atomicAdd per block (block is within batch b) ----
#pragma unroll
    for (int off = 32; off > 0; off >>= 1)
        contrib += __shfl_down(contrib, off, 64);

    __shared__ float wsum[4];
    if (lane == 0) wsum[wid] = contrib;
    __syncthreads();
    if (tid == 0) {
        atomicAdd(&sldj_out[b], wsum[0] + wsum[1] + wsum[2] + wsum[3]);
    }
}

extern "C" void kernel_launch(void* const* d_in, const int* in_sizes, int n_in,
                              void* d_out, int out_size, void* d_ws, size_t ws_size,
                              hipStream_t stream) {
    const float* x    = (const float*)d_in[0];
    const float* a    = (const float*)d_in[1];
    const float* bv   = (const float*)d_in[2];
    const float* pi   = (const float*)d_in[3];
    const float* mu   = (const float*)d_in[4];
    const float* s    = (const float*)d_in[5];
    const float* sldj = (const float*)d_in[6];

    float* out      = (float*)d_out;
    float* sldj_out = out + (size_t)BB * CL;  // outputs concat: out, then sldj

    init_sldj_kernel<<<1, 64, 0, stream>>>(sldj, sldj_out);
    coupling_kernel<<<NBLOCKS, 256, 0, stream>>>(x, a, bv, pi, mu, s, out, sldj_out);
}